// Round 1
// baseline (61.364 us; speedup 1.0000x reference)
//
#include <hip/hip_runtime.h>

typedef unsigned int u32;
typedef unsigned short u16;
typedef __bf16 bf16x8 __attribute__((ext_vector_type(8)));
typedef float f32x4 __attribute__((ext_vector_type(4)));

static __device__ __forceinline__ u16 f2bf(float f) {
  u32 u = __float_as_uint(f);
  return (u16)((u + 0x7fffu + ((u >> 16) & 1u)) >> 16);  // RTNE
}
static __device__ __forceinline__ float b2f(u16 v) {
  return __uint_as_float(((u32)v) << 16);
}
static __device__ __forceinline__ u32 pk2(u16 lo, u16 hi) {
  return (u32)lo | ((u32)hi << 16);
}

// ---- prep: L2-normalize shapelets over s (per (c,k) row), emit bf16 ----
__global__ __launch_bounds__(256) void prep_kernel(const float* __restrict__ sh,
                                                   u16* __restrict__ shn) {
  const int c = blockIdx.x;
  const int lane = threadIdx.x & 63;
  const int w = threadIdx.x >> 6;
  for (int k = w; k < 64; k += 4) {
    float v = sh[(c * 64 + k) * 64 + lane];
    float ss = v * v;
#pragma unroll
    for (int o = 1; o < 64; o <<= 1) ss += __shfl_xor(ss, o, 64);
    float iw = 1.0f / fmaxf(sqrtf(ss), 1e-8f);
    shn[(c * 64 + k) * 64 + lane] = f2bf(v * iw);
  }
}

#define WT 512
#define XS_C 288          // uints per (copy,c): 576 bf16 elems / 2
#define XS_P (16 * XS_C)  // uints per parity copy
#define SHS_STRIDE 72     // padded row stride (bank spread)

// grid (8, 32): blockIdx.x = w-tile (512 w's), blockIdx.y = b.  8 waves.
__global__ __launch_bounds__(512, 2) void main_kernel(const float* __restrict__ x,
                                                      const u16* __restrict__ shn,
                                                      float* __restrict__ out) {
  __shared__ u32 xs2[2 * XS_P];        // 36864 B: bf16 x-slice, 2 parity copies
  __shared__ u16 shs[64 * SHS_STRIDE]; // 9216 B : one channel's shapelets
  __shared__ u16 invwb[16 * WT];       // 16384 B: bf16 inv-window-norms (pre /C)

  const int tid = threadIdx.x;
  const int lane = tid & 63;
  const int wid = tid >> 6;
  const int w0 = blockIdx.x * WT;
  const int b = blockIdx.y;
  const float* xb = x + (size_t)b * 16 * 4096;

  // ---- phase A1: build xs2. copy p holds pairs (2j+p, 2j+1+p) of bf16(x) ----
  for (int it = tid; it < 16 * 36; it += 512) {
    const int c = it / 36;
    const int j0 = (it % 36) * 16;
    const float* xc = xb + c * 4096;
    float xv[20];
    if (w0 + j0 + 19 < 4096) {
#pragma unroll
      for (int q = 0; q < 5; ++q)
        *(float4*)&xv[q * 4] = *(const float4*)&xc[w0 + j0 + q * 4];
    } else {
#pragma unroll
      for (int j = 0; j < 20; ++j) {
        int g = w0 + j0 + j;
        xv[j] = xc[g < 4096 ? g : 4095];
      }
    }
    u16 bf[17];
#pragma unroll
    for (int e = 0; e < 17; ++e) bf[e] = f2bf(xv[e]);
    u32* dst0 = &xs2[c * XS_C + (j0 >> 1)];
    *(uint4*)dst0 =
        make_uint4(pk2(bf[0], bf[1]), pk2(bf[2], bf[3]), pk2(bf[4], bf[5]), pk2(bf[6], bf[7]));
    *(uint4*)(dst0 + 4) =
        make_uint4(pk2(bf[8], bf[9]), pk2(bf[10], bf[11]), pk2(bf[12], bf[13]), pk2(bf[14], bf[15]));
    u32* dst1 = dst0 + XS_P;
    *(uint4*)dst1 =
        make_uint4(pk2(bf[1], bf[2]), pk2(bf[3], bf[4]), pk2(bf[5], bf[6]), pk2(bf[7], bf[8]));
    *(uint4*)(dst1 + 4) =
        make_uint4(pk2(bf[9], bf[10]), pk2(bf[11], bf[12]), pk2(bf[13], bf[14]), pk2(bf[15], bf[16]));
  }

  // ---- phase A2: window inverse norms (fp32 sliding sums; fold 1/C=1/16) ----
  {
    const int c = tid >> 5;
    const int wb = (tid & 31) * 16;
    const float* xc = xb + c * 4096;
    float xv[80];
    if (w0 + wb + 79 < 4096) {
#pragma unroll
      for (int q = 0; q < 20; ++q)
        *(float4*)&xv[q * 4] = *(const float4*)&xc[w0 + wb + q * 4];
    } else {
#pragma unroll
      for (int j = 0; j < 80; ++j) {
        int g = w0 + wb + j;
        xv[j] = xc[g < 4096 ? g : 4095];
      }
    }
    float ss = 0.f;
#pragma unroll
    for (int s = 0; s < 64; ++s) ss += xv[s] * xv[s];
    u16 ov[16];
#pragma unroll
    for (int i = 0; i < 16; ++i) {
      float nrm = sqrtf(fmaxf(ss, 0.f));
      float iw = 0.0625f / fmaxf(nrm, 1e-8f);
      ov[i] = (w0 + wb + i < 4033) ? f2bf(iw) : (u16)0;  // kill padded windows
      ss += xv[64 + i] * xv[64 + i] - xv[i] * xv[i];
    }
    u32* dst = (u32*)&invwb[c * WT + wb];
    *(uint4*)dst =
        make_uint4(pk2(ov[0], ov[1]), pk2(ov[2], ov[3]), pk2(ov[4], ov[5]), pk2(ov[6], ov[7]));
    *(uint4*)(dst + 4) =
        make_uint4(pk2(ov[8], ov[9]), pk2(ov[10], ov[11]), pk2(ov[12], ov[13]), pk2(ov[14], ov[15]));
  }

  // ---- phase B: per-channel MFMA + fp32 rescale-accumulate ----
  f32x4 acc[4][4];
#pragma unroll
  for (int mt = 0; mt < 4; ++mt)
#pragma unroll
    for (int nt = 0; nt < 4; ++nt) acc[mt][nt] = (f32x4){0.f, 0.f, 0.f, 0.f};

  // A-frag: lane (m=lane&15, h=lane>>4) reads elems q0..q0+7, q0 = 64*wid+16*f+m+8h
  const u32* abase = xs2 + (lane & 1) * XS_P;
  const int jbase = 32 * wid + ((lane & 15) >> 1) + 4 * (lane >> 4);
  const int sbase = (lane & 15) * SHS_STRIDE + 8 * (lane >> 4);

  for (int c = 0; c < 16; ++c) {
    __syncthreads();
    {  // stage this channel's normalized shapelets: 64x64 bf16 -> padded LDS
      uint4 v = *(const uint4*)(shn + c * 4096 + tid * 8);
      *(uint4*)&shs[(tid >> 3) * SHS_STRIDE + (tid & 7) * 8] = v;
    }
    __syncthreads();

    const u32* ab = abase + c * XS_C;
    bf16x8 af[6];  // frag depends only on f = mt + 2*ks  (g-sharing)
#pragma unroll
    for (int f = 0; f < 6; ++f) {
      const int jd = jbase + 8 * f;
      uint4 q = make_uint4(ab[jd], ab[jd + 1], ab[jd + 2], ab[jd + 3]);
      af[f] = __builtin_bit_cast(bf16x8, q);
    }
    bf16x8 bfr[4][2];
#pragma unroll
    for (int nt = 0; nt < 4; ++nt)
#pragma unroll
      for (int ks = 0; ks < 2; ++ks)
        bfr[nt][ks] = __builtin_bit_cast(
            bf16x8, *(const uint4*)&shs[sbase + nt * 16 * SHS_STRIDE + ks * 32]);

#pragma unroll
    for (int mt = 0; mt < 4; ++mt) {
      ushort4 r4 = *(const ushort4*)&invwb[c * WT + 64 * wid + 16 * mt + 4 * (lane >> 4)];
      f32x4 iw = {b2f(r4.x), b2f(r4.y), b2f(r4.z), b2f(r4.w)};
#pragma unroll
      for (int nt = 0; nt < 4; ++nt) {
        f32x4 d = {0.f, 0.f, 0.f, 0.f};
        d = __builtin_amdgcn_mfma_f32_16x16x32_bf16(af[mt],     bfr[nt][0], d, 0, 0, 0);
        d = __builtin_amdgcn_mfma_f32_16x16x32_bf16(af[mt + 2], bfr[nt][1], d, 0, 0, 0);
        acc[mt][nt] += iw * d;
      }
    }
  }

  // ---- epilogue: relu + max over this wave's 64 w's, then global atomicMax ----
#pragma unroll
  for (int nt = 0; nt < 4; ++nt) {
    float v = 0.f;  // relu floor
#pragma unroll
    for (int mt = 0; mt < 4; ++mt)
      v = fmaxf(v, fmaxf(fmaxf(acc[mt][nt].x, acc[mt][nt].y),
                         fmaxf(acc[mt][nt].z, acc[mt][nt].w)));
    v = fmaxf(v, __shfl_xor(v, 16, 64));
    v = fmaxf(v, __shfl_xor(v, 32, 64));
    if (lane < 16)
      atomicMax((int*)&out[b * 64 + nt * 16 + lane], __float_as_int(v));
  }
}

extern "C" void kernel_launch(void* const* d_in, const int* in_sizes, int n_in,
                              void* d_out, int out_size, void* d_ws, size_t ws_size,
                              hipStream_t stream) {
  const float* x = (const float*)d_in[0];
  const float* sh = (const float*)d_in[1];
  float* out = (float*)d_out;
  u16* shn = (u16*)d_ws;  // 16*64*64 bf16 = 131072 B

  hipMemsetAsync(d_out, 0, (size_t)out_size * sizeof(float), stream);
  prep_kernel<<<dim3(16), dim3(256), 0, stream>>>(sh, shn);
  main_kernel<<<dim3(8, 32), dim3(512), 0, stream>>>(x, shn, out);
}